// Round 1
// baseline (329.795 us; speedup 1.0000x reference)
//
#include <hip/hip_runtime.h>

// GNN encoder, B=256, N=32, F=256, fully-connected edges (E=992), 2 passes.
// All GEMMs: K=256, N=256, bf16 MFMA 16x16x32, fp32 accum.

typedef short bf16x8 __attribute__((ext_vector_type(8)));
typedef float f32x4 __attribute__((ext_vector_type(4)));

__device__ __forceinline__ float bf2f(unsigned short b) {
    return __uint_as_float(((unsigned)b) << 16);
}
__device__ __forceinline__ unsigned short f2bf(float f) {
    unsigned u = __float_as_uint(f);
    u += 0x7fff + ((u >> 16) & 1);   // RNE
    return (unsigned short)(u >> 16);
}

// ---------------------------------------------------------------------------
// Weight prep: 7 matrices of [K=256][N=256] fp32 (w_e1 split in halves)
// -> transposed [N][K] bf16 so MFMA B-fragments are K-contiguous.
__global__ __launch_bounds__(256) void prep_weights(
    const float* __restrict__ w_in1, const float* __restrict__ w_in2,
    const float* __restrict__ w_e1,  const float* __restrict__ w_e2,
    const float* __restrict__ w_n1,  const float* __restrict__ w_n2,
    unsigned short* __restrict__ dst)
{
    int wid = blockIdx.x >> 8;    // 0..6
    int n   = blockIdx.x & 255;   // output row = input col
    const float* src;
    switch (wid) {
        case 0: src = w_in1; break;
        case 1: src = w_in2; break;
        case 2: src = w_e1; break;              // top half of 512x256
        case 3: src = w_e1 + 256 * 256; break;  // bottom half
        case 4: src = w_e2; break;
        case 5: src = w_n1; break;
        default: src = w_n2; break;
    }
    int k = threadIdx.x;
    dst[((size_t)wid << 16) + (n << 8) + k] = f2bf(src[k * 256 + n]);
}

// x fp32 -> bf16, 8 elements per thread
__global__ __launch_bounds__(256) void conv_x(
    const float* __restrict__ x, unsigned short* __restrict__ xb, int n8)
{
    int i = blockIdx.x * 256 + threadIdx.x;
    if (i >= n8) return;
    const float4* p = (const float4*)x + (size_t)i * 2;
    float4 a = p[0], b = p[1];
    ushort4 o0 = make_ushort4(f2bf(a.x), f2bf(a.y), f2bf(a.z), f2bf(a.w));
    ushort4 o1 = make_ushort4(f2bf(b.x), f2bf(b.y), f2bf(b.z), f2bf(b.w));
    ((ushort4*)xb)[(size_t)i * 2]     = o0;
    ((ushort4*)xb)[(size_t)i * 2 + 1] = o1;
}

// ---------------------------------------------------------------------------
// Generic GEMM: C[M,256] = A[M,256] @ W  with W given transposed [256(n)][256(k)] bf16.
// MODE 0: raw -> bf16 out   (for U, V)
// MODE 1: bias+relu -> bf16 out
// MODE 2: bias+relu -> fp32 out (final)
// Block: 64(M) x 64(N) tile, 4 waves (2x2), each wave 32x32 = 2x2 16x16 frags.
template <int MODE>
__global__ __launch_bounds__(256) void gemm_k256(
    const unsigned short* __restrict__ A,
    const unsigned short* __restrict__ Wt,
    const float* __restrict__ bias,
    void* __restrict__ out)
{
    __shared__ unsigned short As[64][40];  // +8 pad -> conflict-free b128 reads
    __shared__ unsigned short Bs[64][40];

    const int m0 = blockIdx.x * 64;
    const int n0 = blockIdx.y * 64;
    const int t = threadIdx.x;
    const int lane = t & 63;
    const int wave = t >> 6;
    const int wm = wave >> 1, wn = wave & 1;
    const int srow = t >> 2;
    const int skc = (t & 3) * 8;
    const int lr = lane & 15;
    const int lk = (lane >> 4) * 8;

    f32x4 acc[2][2] = {};

    for (int kb = 0; kb < 256; kb += 32) {
        *(uint4*)&As[srow][skc] = *(const uint4*)&A[(size_t)(m0 + srow) * 256 + kb + skc];
        *(uint4*)&Bs[srow][skc] = *(const uint4*)&Wt[(size_t)(n0 + srow) * 256 + kb + skc];
        __syncthreads();
        bf16x8 a0 = *(const bf16x8*)&As[wm * 32 + lr][lk];
        bf16x8 a1 = *(const bf16x8*)&As[wm * 32 + 16 + lr][lk];
        bf16x8 b0 = *(const bf16x8*)&Bs[wn * 32 + lr][lk];
        bf16x8 b1 = *(const bf16x8*)&Bs[wn * 32 + 16 + lr][lk];
        acc[0][0] = __builtin_amdgcn_mfma_f32_16x16x32_bf16(a0, b0, acc[0][0], 0, 0, 0);
        acc[0][1] = __builtin_amdgcn_mfma_f32_16x16x32_bf16(a0, b1, acc[0][1], 0, 0, 0);
        acc[1][0] = __builtin_amdgcn_mfma_f32_16x16x32_bf16(a1, b0, acc[1][0], 0, 0, 0);
        acc[1][1] = __builtin_amdgcn_mfma_f32_16x16x32_bf16(a1, b1, acc[1][1], 0, 0, 0);
        __syncthreads();
    }

    const int rowb = m0 + wm * 32;
    const int colb = n0 + wn * 32;
#pragma unroll
    for (int fm = 0; fm < 2; fm++)
#pragma unroll
        for (int fn = 0; fn < 2; fn++) {
            int col = colb + fn * 16 + lr;
            float bv = 0.f;
            if constexpr (MODE != 0) bv = bias[col];
#pragma unroll
            for (int r = 0; r < 4; r++) {
                int row = rowb + fm * 16 + (lane >> 4) * 4 + r;
                float v = acc[fm][fn][r];
                if constexpr (MODE != 0) { v += bv; v = v > 0.f ? v : 0.f; }
                if constexpr (MODE == 2)
                    ((float*)out)[(size_t)row * 256 + col] = v;
                else
                    ((unsigned short*)out)[(size_t)row * 256 + col] = f2bf(v);
            }
        }
}

// ---------------------------------------------------------------------------
// Fused edge layer-2 + scatter-mean.
// Virtual rows: per (batch b, receiver j): 32 slots, slot s<31 -> sender i=s+(s>=j),
// slot 31 = dummy (excluded from sum). A row = relu(U[b,i]+V[b,j]+b_e1), built on
// the fly into LDS. C-tile epilogue: relu(acc+b_e2), row-sum over 31 real slots,
// /31, -> agg[b,j] bf16. Block = 64 rows (2 receivers) x 64 cols.
__global__ __launch_bounds__(256) void edge_fused(
    const unsigned short* __restrict__ U,
    const unsigned short* __restrict__ V,
    const float* __restrict__ b1,
    const unsigned short* __restrict__ Wt2,
    const float* __restrict__ b2,
    unsigned short* __restrict__ agg)
{
    __shared__ unsigned short As[64][40];
    __shared__ unsigned short Bs[64][40];
    __shared__ float Cs[64][66];

    const int g0 = blockIdx.x * 2;   // global node index (b*32+j), pair
    const int b  = g0 >> 5;
    const int j0 = g0 & 31;
    const int n0 = blockIdx.y * 64;
    const int t = threadIdx.x;
    const int lane = t & 63;
    const int wave = t >> 6;
    const int wm = wave >> 1, wn = wave & 1;
    const int srow = t >> 2;
    const int skc = (t & 3) * 8;
    const int lr = lane & 15;
    const int lk = (lane >> 4) * 8;

    const int jj = j0 + (srow >> 5);
    const int s  = srow & 31;
    const int si = (s == 31) ? jj : (s + (s >= jj ? 1 : 0));
    const size_t urow = (size_t)(b * 32 + si) * 256;
    const size_t vrow = (size_t)(b * 32 + jj) * 256;

    f32x4 acc[2][2] = {};

    for (int kb = 0; kb < 256; kb += 32) {
        union { uint4 q; unsigned short u[8]; } Ua, Va, Eo;
        Ua.q = *(const uint4*)&U[urow + kb + skc];
        Va.q = *(const uint4*)&V[vrow + kb + skc];
#pragma unroll
        for (int e = 0; e < 8; e++) {
            float val = bf2f(Ua.u[e]) + bf2f(Va.u[e]) + b1[kb + skc + e];
            Eo.u[e] = f2bf(val > 0.f ? val : 0.f);
        }
        *(uint4*)&As[srow][skc] = Eo.q;
        *(uint4*)&Bs[srow][skc] = *(const uint4*)&Wt2[(size_t)(n0 + srow) * 256 + kb + skc];
        __syncthreads();
        bf16x8 a0 = *(const bf16x8*)&As[wm * 32 + lr][lk];
        bf16x8 a1 = *(const bf16x8*)&As[wm * 32 + 16 + lr][lk];
        bf16x8 b0 = *(const bf16x8*)&Bs[wn * 32 + lr][lk];
        bf16x8 b1 = *(const bf16x8*)&Bs[wn * 32 + 16 + lr][lk];
        acc[0][0] = __builtin_amdgcn_mfma_f32_16x16x32_bf16(a0, b0, acc[0][0], 0, 0, 0);
        acc[0][1] = __builtin_amdgcn_mfma_f32_16x16x32_bf16(a0, b1, acc[0][1], 0, 0, 0);
        acc[1][0] = __builtin_amdgcn_mfma_f32_16x16x32_bf16(a1, b0, acc[1][0], 0, 0, 0);
        acc[1][1] = __builtin_amdgcn_mfma_f32_16x16x32_bf16(a1, b1, acc[1][1], 0, 0, 0);
        __syncthreads();
    }

    // bias + relu -> Cs
#pragma unroll
    for (int fm = 0; fm < 2; fm++)
#pragma unroll
        for (int fn = 0; fn < 2; fn++) {
            int col = wn * 32 + fn * 16 + lr;
            float bv = b2[n0 + col];
#pragma unroll
            for (int r = 0; r < 4; r++) {
                int row = wm * 32 + fm * 16 + (lane >> 4) * 4 + r;
                float v = acc[fm][fn][r] + bv;
                Cs[row][col] = v > 0.f ? v : 0.f;
            }
        }
    __syncthreads();

    if (t < 128) {
        int rr = t >> 6;    // which receiver of the pair
        int col = t & 63;
        float sum = 0.f;
#pragma unroll
        for (int s2 = 0; s2 < 31; s2++) sum += Cs[rr * 32 + s2][col];
        sum *= (1.0f / 31.0f);
        agg[(size_t)(b * 32 + j0 + rr) * 256 + n0 + col] = f2bf(sum);
    }
}

// ---------------------------------------------------------------------------
extern "C" void kernel_launch(void* const* d_in, const int* in_sizes, int n_in,
                              void* d_out, int out_size, void* d_ws, size_t ws_size,
                              hipStream_t stream)
{
    const float* x     = (const float*)d_in[0];
    const float* w_in1 = (const float*)d_in[3];
    const float* b_in1 = (const float*)d_in[4];
    const float* w_in2 = (const float*)d_in[5];
    const float* b_in2 = (const float*)d_in[6];
    const float* w_e1  = (const float*)d_in[7];
    const float* b_e1  = (const float*)d_in[8];
    const float* w_e2  = (const float*)d_in[9];
    const float* b_e2  = (const float*)d_in[10];
    const float* w_n1  = (const float*)d_in[11];
    const float* b_n1  = (const float*)d_in[12];
    const float* w_n2  = (const float*)d_in[13];
    const float* b_n2  = (const float*)d_in[14];

    char* ws = (char*)d_ws;
    size_t off = 0;
    auto alloc = [&](size_t n) { char* p = ws + off; off += (n + 255) & ~(size_t)255; return p; };

    unsigned short* wt = (unsigned short*)alloc(7 * 65536 * sizeof(unsigned short));
    unsigned short* xb = (unsigned short*)alloc(8192 * 256 * 2);
    unsigned short* h  = (unsigned short*)alloc(8192 * 256 * 2);
    unsigned short* t1 = (unsigned short*)alloc(8192 * 256 * 2);
    unsigned short* Ub = (unsigned short*)alloc(8192 * 256 * 2);
    unsigned short* Vb = (unsigned short*)alloc(8192 * 256 * 2);
    unsigned short* ag = (unsigned short*)alloc(8192 * 256 * 2);
    (void)ws_size; (void)in_sizes; (void)n_in; (void)out_size;

    prep_weights<<<7 * 256, 256, 0, stream>>>(w_in1, w_in2, w_e1, w_e2, w_n1, w_n2, wt);
    conv_x<<<1024, 256, 0, stream>>>(x, xb, 262144);

    dim3 gs(8192 / 64, 4);
    gemm_k256<1><<<gs, 256, 0, stream>>>(xb, wt + 0 * 65536, b_in1, t1);
    gemm_k256<1><<<gs, 256, 0, stream>>>(t1, wt + 1 * 65536, b_in2, h);

    for (int p = 0; p < 2; p++) {
        gemm_k256<0><<<gs, 256, 0, stream>>>(h, wt + 2 * 65536, nullptr, Ub);
        gemm_k256<0><<<gs, 256, 0, stream>>>(h, wt + 3 * 65536, nullptr, Vb);
        dim3 ge(4096, 4);
        edge_fused<<<ge, 256, 0, stream>>>(Ub, Vb, b_e1, wt + 4 * 65536, b_e2, ag);
        gemm_k256<1><<<gs, 256, 0, stream>>>(ag, wt + 5 * 65536, b_n1, t1);
        if (p == 0)
            gemm_k256<1><<<gs, 256, 0, stream>>>(t1, wt + 6 * 65536, b_n2, h);
        else
            gemm_k256<2><<<gs, 256, 0, stream>>>(t1, wt + 6 * 65536, b_n2, (float*)d_out);
    }
}

// Round 2
// 194.693 us; speedup vs baseline: 1.6939x; 1.6939x over previous
//
#include <hip/hip_runtime.h>

// GNN encoder, B=256, N=32, F=256, fully-connected edges, 2 passes.
// All GEMMs: K=256, bf16 MFMA 16x16x32, fp32 accum.

typedef short bf16x8 __attribute__((ext_vector_type(8)));
typedef float f32x4 __attribute__((ext_vector_type(4)));

__device__ __forceinline__ float bf2f(unsigned short b) {
    return __uint_as_float(((unsigned)b) << 16);
}
__device__ __forceinline__ unsigned short f2bf(float f) {
    unsigned u = __float_as_uint(f);
    u += 0x7fff + ((u >> 16) & 1);   // RNE
    return (unsigned short)(u >> 16);
}

// ---------------------------------------------------------------------------
// Weight prep: 7 matrices of [K=256][N=256] fp32 (w_e1 split in halves)
// -> transposed [N][K] bf16 so MFMA B-fragments are K-contiguous.
__global__ __launch_bounds__(256) void prep_weights(
    const float* __restrict__ w_in1, const float* __restrict__ w_in2,
    const float* __restrict__ w_e1,  const float* __restrict__ w_e2,
    const float* __restrict__ w_n1,  const float* __restrict__ w_n2,
    unsigned short* __restrict__ dst)
{
    int wid = blockIdx.x >> 8;    // 0..6
    int n   = blockIdx.x & 255;   // output row = input col
    const float* src;
    switch (wid) {
        case 0: src = w_in1; break;
        case 1: src = w_in2; break;
        case 2: src = w_e1; break;              // top half of 512x256
        case 3: src = w_e1 + 256 * 256; break;  // bottom half
        case 4: src = w_e2; break;
        case 5: src = w_n1; break;
        default: src = w_n2; break;
    }
    int k = threadIdx.x;
    dst[((size_t)wid << 16) + (n << 8) + k] = f2bf(src[k * 256 + n]);
}

// x fp32 -> bf16, 8 elements per thread
__global__ __launch_bounds__(256) void conv_x(
    const float* __restrict__ x, unsigned short* __restrict__ xb, int n8)
{
    int i = blockIdx.x * 256 + threadIdx.x;
    if (i >= n8) return;
    const float4* p = (const float4*)x + (size_t)i * 2;
    float4 a = p[0], b = p[1];
    ushort4 o0 = make_ushort4(f2bf(a.x), f2bf(a.y), f2bf(a.z), f2bf(a.w));
    ushort4 o1 = make_ushort4(f2bf(b.x), f2bf(b.y), f2bf(b.z), f2bf(b.w));
    ((ushort4*)xb)[(size_t)i * 2]     = o0;
    ((ushort4*)xb)[(size_t)i * 2 + 1] = o1;
}

// ---------------------------------------------------------------------------
// Generic GEMM: C[M, n-tile] = A[M,256] @ Wt  (Wt transposed [n][k] bf16).
// MODE 0: raw -> bf16 out   (UV fused, ldc=512)
// MODE 1: bias+relu -> bf16 out
// MODE 2: bias+relu -> fp32 out (final)
template <int MODE>
__global__ __launch_bounds__(256) void gemm_k256(
    const unsigned short* __restrict__ A,
    const unsigned short* __restrict__ Wt,
    const float* __restrict__ bias,
    void* __restrict__ out, int ldc)
{
    __shared__ unsigned short As[64][40];  // +8 pad
    __shared__ unsigned short Bs[64][40];

    const int m0 = blockIdx.x * 64;
    const int n0 = blockIdx.y * 64;
    const int t = threadIdx.x;
    const int lane = t & 63;
    const int wave = t >> 6;
    const int wm = wave >> 1, wn = wave & 1;
    const int srow = t >> 2;
    const int skc = (t & 3) * 8;
    const int lr = lane & 15;
    const int lk = (lane >> 4) * 8;

    f32x4 acc[2][2] = {};

    for (int kb = 0; kb < 256; kb += 32) {
        *(uint4*)&As[srow][skc] = *(const uint4*)&A[(size_t)(m0 + srow) * 256 + kb + skc];
        *(uint4*)&Bs[srow][skc] = *(const uint4*)&Wt[(size_t)(n0 + srow) * 256 + kb + skc];
        __syncthreads();
        bf16x8 a0 = *(const bf16x8*)&As[wm * 32 + lr][lk];
        bf16x8 a1 = *(const bf16x8*)&As[wm * 32 + 16 + lr][lk];
        bf16x8 b0 = *(const bf16x8*)&Bs[wn * 32 + lr][lk];
        bf16x8 b1 = *(const bf16x8*)&Bs[wn * 32 + 16 + lr][lk];
        acc[0][0] = __builtin_amdgcn_mfma_f32_16x16x32_bf16(a0, b0, acc[0][0], 0, 0, 0);
        acc[0][1] = __builtin_amdgcn_mfma_f32_16x16x32_bf16(a0, b1, acc[0][1], 0, 0, 0);
        acc[1][0] = __builtin_amdgcn_mfma_f32_16x16x32_bf16(a1, b0, acc[1][0], 0, 0, 0);
        acc[1][1] = __builtin_amdgcn_mfma_f32_16x16x32_bf16(a1, b1, acc[1][1], 0, 0, 0);
        __syncthreads();
    }

    const int rowb = m0 + wm * 32;
    const int colb = n0 + wn * 32;
#pragma unroll
    for (int fm = 0; fm < 2; fm++)
#pragma unroll
        for (int fn = 0; fn < 2; fn++) {
            int col = colb + fn * 16 + lr;
            float bv = 0.f;
            if constexpr (MODE != 0) bv = bias[col];
#pragma unroll
            for (int r = 0; r < 4; r++) {
                int row = rowb + fm * 16 + (lane >> 4) * 4 + r;
                float v = acc[fm][fn][r];
                if constexpr (MODE != 0) { v += bv; v = v > 0.f ? v : 0.f; }
                if constexpr (MODE == 2)
                    ((float*)out)[(size_t)row * ldc + col] = v;
                else
                    ((unsigned short*)out)[(size_t)row * ldc + col] = f2bf(v);
            }
        }
}

// ---------------------------------------------------------------------------
// Fused edge layer-2 + scatter-mean, full-N per block.
// Block: 64 virtual rows (2 receivers x 32 slots; slot 31 dummy) x N=256.
// 4 waves, wave w owns cols [w*64, w*64+64). A built on the fly from
// UV (interleaved [node][512]: U=0..255, V=256..511). Epilogue: bias+relu,
// register row-sum over 31 real slots via shfl_xor, /31 -> agg bf16.
__global__ __launch_bounds__(256) void edge_fused(
    const unsigned short* __restrict__ UV,
    const float* __restrict__ b1,
    const unsigned short* __restrict__ Wt2,
    const float* __restrict__ b2,
    unsigned short* __restrict__ agg)
{
    __shared__ unsigned short As[64][40];
    __shared__ unsigned short Bs[256][40];

    // XCD-aware swizzle: 4096 blocks % 8 == 0 -> consecutive logical ids per XCD
    const int logical = (blockIdx.x & 7) * 512 + (blockIdx.x >> 3);
    const int g0 = logical * 2;      // node index (b*32+j), pair
    const int b  = g0 >> 5;
    const int j0 = g0 & 31;
    const int t = threadIdx.x;
    const int lane = t & 63;
    const int wave = t >> 6;
    const int srow = t >> 2;         // 0..63
    const int skc = (t & 3) * 8;     // 0,8,16,24
    const int lr = lane & 15;
    const int lk = (lane >> 4) * 8;

    // which virtual row this thread stages
    const int jj = j0 + (srow >> 5);
    const int s  = srow & 31;
    const int si = (s == 31) ? jj : (s + (s >= jj ? 1 : 0));
    const size_t urow = (size_t)(b * 32 + si) * 512;
    const size_t vrow = (size_t)(b * 32 + jj) * 512 + 256;

    f32x4 acc[4][4] = {};

    for (int kb = 0; kb < 256; kb += 32) {
        // A: build relu(U+V+b1) rows
        union { uint4 q; unsigned short u[8]; } Ua, Va, Eo;
        Ua.q = *(const uint4*)&UV[urow + kb + skc];
        Va.q = *(const uint4*)&UV[vrow + kb + skc];
#pragma unroll
        for (int e = 0; e < 8; e++) {
            float val = bf2f(Ua.u[e]) + bf2f(Va.u[e]) + b1[kb + skc + e];
            Eo.u[e] = f2bf(val > 0.f ? val : 0.f);
        }
        *(uint4*)&As[srow][skc] = Eo.q;
        // B: 256 n-rows x 32 k
#pragma unroll
        for (int q = 0; q < 4; q++)
            *(uint4*)&Bs[q * 64 + srow][skc] =
                *(const uint4*)&Wt2[(size_t)(q * 64 + srow) * 256 + kb + skc];
        __syncthreads();

        bf16x8 af[4], bf[4];
#pragma unroll
        for (int fm = 0; fm < 4; fm++) af[fm] = *(const bf16x8*)&As[fm * 16 + lr][lk];
#pragma unroll
        for (int fn = 0; fn < 4; fn++) bf[fn] = *(const bf16x8*)&Bs[wave * 64 + fn * 16 + lr][lk];
#pragma unroll
        for (int fm = 0; fm < 4; fm++)
#pragma unroll
            for (int fn = 0; fn < 4; fn++)
                acc[fm][fn] = __builtin_amdgcn_mfma_f32_16x16x32_bf16(af[fm], bf[fn], acc[fm][fn], 0, 0, 0);
        __syncthreads();
    }

    // Epilogue: bias + relu, sum rows 0..30 (per receiver), /31, write bf16.
    const int lg = lane >> 4;        // lane group 0..3
#pragma unroll
    for (int fn = 0; fn < 4; fn++) {
        const int col = wave * 64 + fn * 16 + lr;
        const float bv = b2[col];
#pragma unroll
        for (int recv = 0; recv < 2; recv++) {
            float sum = 0.f;
#pragma unroll
            for (int fh = 0; fh < 2; fh++) {
                const int fm = recv * 2 + fh;
#pragma unroll
                for (int r = 0; r < 4; r++) {
                    const int rowin32 = fh * 16 + lg * 4 + r;   // 0..31 within receiver
                    float v = acc[fm][fn][r] + bv;
                    v = v > 0.f ? v : 0.f;
                    if (rowin32 != 31) sum += v;                // exclude dummy slot
                }
            }
            sum += __shfl_xor(sum, 16);
            sum += __shfl_xor(sum, 32);
            if (lane < 16)
                agg[(size_t)(g0 + recv) * 256 + col] = f2bf(sum * (1.0f / 31.0f));
        }
    }
}

// ---------------------------------------------------------------------------
extern "C" void kernel_launch(void* const* d_in, const int* in_sizes, int n_in,
                              void* d_out, int out_size, void* d_ws, size_t ws_size,
                              hipStream_t stream)
{
    const float* x     = (const float*)d_in[0];
    const float* w_in1 = (const float*)d_in[3];
    const float* b_in1 = (const float*)d_in[4];
    const float* w_in2 = (const float*)d_in[5];
    const float* b_in2 = (const float*)d_in[6];
    const float* w_e1  = (const float*)d_in[7];
    const float* b_e1  = (const float*)d_in[8];
    const float* w_e2  = (const float*)d_in[9];
    const float* b_e2  = (const float*)d_in[10];
    const float* w_n1  = (const float*)d_in[11];
    const float* b_n1  = (const float*)d_in[12];
    const float* w_n2  = (const float*)d_in[13];
    const float* b_n2  = (const float*)d_in[14];

    char* ws = (char*)d_ws;
    size_t off = 0;
    auto alloc = [&](size_t n) { char* p = ws + off; off += (n + 255) & ~(size_t)255; return p; };

    unsigned short* wt = (unsigned short*)alloc(7 * 65536 * sizeof(unsigned short));
    unsigned short* xb = (unsigned short*)alloc(8192 * 256 * 2);
    unsigned short* h  = (unsigned short*)alloc(8192 * 256 * 2);
    unsigned short* t1 = (unsigned short*)alloc(8192 * 256 * 2);
    unsigned short* UV = (unsigned short*)alloc(8192 * 512 * 2);
    unsigned short* ag = (unsigned short*)alloc(8192 * 256 * 2);
    (void)ws_size; (void)in_sizes; (void)n_in; (void)out_size;

    prep_weights<<<7 * 256, 256, 0, stream>>>(w_in1, w_in2, w_e1, w_e2, w_n1, w_n2, wt);
    conv_x<<<1024, 256, 0, stream>>>(x, xb, 262144);

    dim3 gs(8192 / 64, 4);
    gemm_k256<1><<<gs, 256, 0, stream>>>(xb, wt + 0 * 65536, b_in1, t1, 256);
    gemm_k256<1><<<gs, 256, 0, stream>>>(t1, wt + 1 * 65536, b_in2, h, 256);

    for (int p = 0; p < 2; p++) {
        // U,V fused: N=512 (w_e1 halves adjacent at wt+2*65536), out interleaved ldc=512
        dim3 guv(8192 / 64, 8);
        gemm_k256<0><<<guv, 256, 0, stream>>>(h, wt + 2 * 65536, nullptr, UV, 512);
        edge_fused<<<4096, 256, 0, stream>>>(UV, b_e1, wt + 4 * 65536, b_e2, ag);
        gemm_k256<1><<<gs, 256, 0, stream>>>(ag, wt + 5 * 65536, b_n1, t1, 256);
        if (p == 0)
            gemm_k256<1><<<gs, 256, 0, stream>>>(t1, wt + 6 * 65536, b_n2, h, 256);
        else
            gemm_k256<2><<<gs, 256, 0, stream>>>(t1, wt + 6 * 65536, b_n2, (float*)d_out, 256);
    }
}

// Round 3
// 165.869 us; speedup vs baseline: 1.9883x; 1.1738x over previous
//
#include <hip/hip_runtime.h>

// GNN encoder, B=256, N=32, F=256, fully-connected edges, 2 passes.
// bf16 MFMA 16x16x32, fp32 accum. Weights pre-swizzled into LDS-image layout,
// staged via global_load_lds; XOR chunk-swizzle (c' = c ^ ((row>>1)&3)) on all
// LDS tiles; 1-barrier double-buffered K-loops.

typedef short bf16x8 __attribute__((ext_vector_type(8)));
typedef float f32x4 __attribute__((ext_vector_type(4)));
typedef unsigned short ushort_t;

__device__ __forceinline__ unsigned short f2bf(float f) {
    unsigned u = __float_as_uint(f);
    u += 0x7fff + ((u >> 16) & 1);   // RNE
    return (unsigned short)(u >> 16);
}
__device__ __forceinline__ unsigned cvt_pk_bf16(float lo, float hi) {
    unsigned r;
    asm volatile("v_cvt_pk_bf16_f32 %0, %1, %2" : "=v"(r) : "v"(lo), "v"(hi));
    return r;
}
__device__ __forceinline__ void gload16(const void* g, void* l) {
    __builtin_amdgcn_global_load_lds(
        (const __attribute__((address_space(1))) void*)g,
        (__attribute__((address_space(3))) void*)l, 16, 0, 0);
}

// ---------------------------------------------------------------------------
// Weight prep: logical Wt[n][k] (n=output col, k contiguous) -> swizzled LDS
// image: ushort idx = kb*8192 + n*32 + (kc ^ ((n>>1)&3))*8 + (k&7), kb=k>>5.
__global__ __launch_bounds__(256) void prep_weights(
    const float* __restrict__ w_in1, const float* __restrict__ w_in2,
    const float* __restrict__ w_e1,  const float* __restrict__ w_e2,
    const float* __restrict__ w_n1,  const float* __restrict__ w_n2,
    ushort_t* __restrict__ dst)
{
    __shared__ ushort_t tile[32][264];
    const int wid = blockIdx.x >> 3;   // 0..6
    const int kb  = blockIdx.x & 7;
    const float* src;
    switch (wid) {
        case 0: src = w_in1; break;
        case 1: src = w_in2; break;
        case 2: src = w_e1; break;              // top half (send side)
        case 3: src = w_e1 + 65536; break;      // bottom half (recv side)
        case 4: src = w_e2; break;
        case 5: src = w_n1; break;
        default: src = w_n2; break;
    }
    const int t = threadIdx.x;
#pragma unroll
    for (int k0 = 0; k0 < 32; k0++)
        tile[k0][t] = f2bf(src[(size_t)(kb * 32 + k0) * 256 + t]);  // coalesced
    __syncthreads();
    ushort_t* base = dst + wid * 65536 + kb * 8192 + t * 32;
    const int sw = (t >> 1) & 3;
#pragma unroll
    for (int kc = 0; kc < 4; kc++) {
        union { uint4 q; ushort_t u[8]; } w;
#pragma unroll
        for (int ko = 0; ko < 8; ko++) w.u[ko] = tile[kc * 8 + ko][t];
        *(uint4*)&base[(kc ^ sw) * 8] = w.q;
    }
}

// x fp32 -> bf16
__global__ __launch_bounds__(256) void conv_x(
    const float* __restrict__ x, ushort_t* __restrict__ xb, int n8)
{
    int i = blockIdx.x * 256 + threadIdx.x;
    if (i >= n8) return;
    const float4* p = (const float4*)x + (size_t)i * 2;
    float4 a = p[0], b = p[1];
    ushort4 o0 = make_ushort4(f2bf(a.x), f2bf(a.y), f2bf(a.z), f2bf(a.w));
    ushort4 o1 = make_ushort4(f2bf(b.x), f2bf(b.y), f2bf(b.z), f2bf(b.w));
    ((ushort4*)xb)[(size_t)i * 2]     = o0;
    ((ushort4*)xb)[(size_t)i * 2 + 1] = o1;
}

// ---------------------------------------------------------------------------
// Direct GEMM: C[8192, 256-slice] = A[8192,256](bf16) @ W. Tile 64x64, 4 waves
// (2x2), gload_lds staging for A (pre-swizzled per-lane source) and B
// (pre-swizzled weight image), 1-barrier dbuf loop.
// EPI: 0 raw f32, 1 bias f32, 2 bias+relu bf16, 3 bias+relu f32
template <int EPI>
__global__ __launch_bounds__(256) void gemm64(
    const ushort_t* __restrict__ A, const ushort_t* __restrict__ WB,
    const float* __restrict__ bias, void* __restrict__ out, int ldc)
{
    __shared__ ushort_t As[2][2048];
    __shared__ ushort_t Bs[2][2048];

    const int mb = (blockIdx.x & 7) * 16 + (blockIdx.x >> 3);  // XCD swizzle, 128%8==0
    const int m0 = mb * 64;
    const int n0 = blockIdx.y * 64;
    const int t = threadIdx.x;
    const int lane = t & 63;
    const int w = t >> 6;
    const int wm = w >> 1, wn = w & 1;
    const int lr = lane & 15, lg = lane >> 4;

    // A per-lane pre-swizzled source: lane fills LDS chunk lane (linear)
    const int arow = w * 16 + (lane >> 2);
    const int ac = (lane & 3) ^ ((arow >> 1) & 3);     // logical k-chunk
    const ushort_t* asrc = A + (size_t)(m0 + arow) * 256 + ac * 8;
    const ushort_t* bsrc = WB + n0 * 32 + w * 512 + lane * 8;

    int aoff[2], boff[2];
#pragma unroll
    for (int f = 0; f < 2; f++) {
        int r = wm * 32 + f * 16 + lr;
        aoff[f] = r * 32 + ((lg ^ ((r >> 1) & 3)) * 8);
        int rb = wn * 32 + f * 16 + lr;
        boff[f] = rb * 32 + ((lg ^ ((rb >> 1) & 3)) * 8);
    }

    f32x4 acc[2][2] = {};

    // prologue stage
    gload16(asrc, &As[0][w * 512]);
    gload16(bsrc, &Bs[0][w * 512]);

    for (int kb = 1; kb < 8; kb++) {
        __syncthreads();
        gload16(asrc + kb * 32,   &As[kb & 1][w * 512]);
        gload16(bsrc + kb * 8192, &Bs[kb & 1][w * 512]);
        const int cur = (kb - 1) & 1;
        bf16x8 a0 = *(const bf16x8*)&As[cur][aoff[0]];
        bf16x8 a1 = *(const bf16x8*)&As[cur][aoff[1]];
        bf16x8 b0 = *(const bf16x8*)&Bs[cur][boff[0]];
        bf16x8 b1 = *(const bf16x8*)&Bs[cur][boff[1]];
        acc[0][0] = __builtin_amdgcn_mfma_f32_16x16x32_bf16(a0, b0, acc[0][0], 0, 0, 0);
        acc[0][1] = __builtin_amdgcn_mfma_f32_16x16x32_bf16(a0, b1, acc[0][1], 0, 0, 0);
        acc[1][0] = __builtin_amdgcn_mfma_f32_16x16x32_bf16(a1, b0, acc[1][0], 0, 0, 0);
        acc[1][1] = __builtin_amdgcn_mfma_f32_16x16x32_bf16(a1, b1, acc[1][1], 0, 0, 0);
    }
    __syncthreads();
    {
        bf16x8 a0 = *(const bf16x8*)&As[1][aoff[0]];
        bf16x8 a1 = *(const bf16x8*)&As[1][aoff[1]];
        bf16x8 b0 = *(const bf16x8*)&Bs[1][boff[0]];
        bf16x8 b1 = *(const bf16x8*)&Bs[1][boff[1]];
        acc[0][0] = __builtin_amdgcn_mfma_f32_16x16x32_bf16(a0, b0, acc[0][0], 0, 0, 0);
        acc[0][1] = __builtin_amdgcn_mfma_f32_16x16x32_bf16(a0, b1, acc[0][1], 0, 0, 0);
        acc[1][0] = __builtin_amdgcn_mfma_f32_16x16x32_bf16(a1, b0, acc[1][0], 0, 0, 0);
        acc[1][1] = __builtin_amdgcn_mfma_f32_16x16x32_bf16(a1, b1, acc[1][1], 0, 0, 0);
    }

#pragma unroll
    for (int fm = 0; fm < 2; fm++)
#pragma unroll
        for (int fn = 0; fn < 2; fn++) {
            const int col = n0 + wn * 32 + fn * 16 + lr;
            float bv = 0.f;
            if constexpr (EPI != 0) bv = bias[col];
#pragma unroll
            for (int r = 0; r < 4; r++) {
                const int row = m0 + wm * 32 + fm * 16 + lg * 4 + r;
                float v = acc[fm][fn][r] + bv;
                if constexpr (EPI >= 2) v = fmaxf(v, 0.f);
                if constexpr (EPI == 2)
                    ((ushort_t*)out)[(size_t)row * ldc + col] = f2bf(v);
                else
                    ((float*)out)[(size_t)row * ldc + col] = v;
            }
        }
}

// ---------------------------------------------------------------------------
// Fused edge layer-2 + scatter-mean. 128 virtual rows (4 receivers x 32 slots,
// slot 31 dummy) x N=256. 8 waves (2m x 4n), each 64x64 out. A rows built on
// the fly: relu(U'[send] + V[recv]) from f32 UV (b_e1 pre-folded into U').
__global__ __launch_bounds__(512) void edge_fused(
    const float* __restrict__ UV,       // [8192][512] f32: U' | V
    const ushort_t* __restrict__ WB,    // swizzled w_e2 image
    const float* __restrict__ b2,
    ushort_t* __restrict__ agg)         // [8192][256] bf16
{
    __shared__ ushort_t As[2][4096];    // 128 rows x 32 k
    __shared__ ushort_t Bs[2][8192];    // 256 rows x 32 k

    const int logical = (blockIdx.x & 7) * 256 + (blockIdx.x >> 3);  // 2048%8==0
    const int g0 = logical * 4;         // first node (batch*32 + j)
    const int bb = g0 >> 5;
    const int j0 = g0 & 31;
    const int t = threadIdx.x;
    const int lane = t & 63;
    const int w = t >> 6;
    const int wm = w >> 2, wn = w & 3;
    const int lr = lane & 15, lg = lane >> 4;

    // A-build mapping (per-thread constant)
    const int arow = t >> 2;            // 0..127
    const int ac = t & 3;               // logical k-chunk
    const int jr = arow >> 5;
    const int s = arow & 31;
    const int j = j0 + jr;
    const int si = (s == 31) ? j : (s + (s >= j ? 1 : 0));
    const float* up = UV + (size_t)(bb * 32 + si) * 512 + ac * 8;
    const float* vp = UV + (size_t)(bb * 32 + j) * 512 + 256 + ac * 8;
    const int awoff = arow * 32 + ((ac ^ ((arow >> 1) & 3)) * 8);

    const ushort_t* bsrc0 = WB + (2 * w) * 512 + lane * 8;
    const ushort_t* bsrc1 = WB + (2 * w + 1) * 512 + lane * 8;

    int aoff[4], boff[4];
#pragma unroll
    for (int f = 0; f < 4; f++) {
        int r = wm * 64 + f * 16 + lr;
        aoff[f] = r * 32 + ((lg ^ ((r >> 1) & 3)) * 8);
        int rb = wn * 64 + f * 16 + lr;
        boff[f] = rb * 32 + ((lg ^ ((rb >> 1) & 3)) * 8);
    }

    f32x4 acc[4][4] = {};

    // prologue: build buffer 0
    {
        float4 u0 = *(const float4*)up,       u1 = *(const float4*)(up + 4);
        float4 v0 = *(const float4*)vp,       v1 = *(const float4*)(vp + 4);
        gload16(bsrc0, &Bs[0][(2 * w) * 512]);
        gload16(bsrc1, &Bs[0][(2 * w + 1) * 512]);
        uint4 q;
        q.x = cvt_pk_bf16(fmaxf(u0.x + v0.x, 0.f), fmaxf(u0.y + v0.y, 0.f));
        q.y = cvt_pk_bf16(fmaxf(u0.z + v0.z, 0.f), fmaxf(u0.w + v0.w, 0.f));
        q.z = cvt_pk_bf16(fmaxf(u1.x + v1.x, 0.f), fmaxf(u1.y + v1.y, 0.f));
        q.w = cvt_pk_bf16(fmaxf(u1.z + v1.z, 0.f), fmaxf(u1.w + v1.w, 0.f));
        *(uint4*)&As[0][awoff] = q;
    }

    for (int kb = 1; kb < 8; kb++) {
        __syncthreads();
        const int nb = kb & 1, cb = nb ^ 1;
        // issue next-tile loads early (T14)
        float4 u0 = *(const float4*)(up + kb * 32),     u1 = *(const float4*)(up + kb * 32 + 4);
        float4 v0 = *(const float4*)(vp + kb * 32),     v1 = *(const float4*)(vp + kb * 32 + 4);
        gload16(bsrc0 + kb * 8192, &Bs[nb][(2 * w) * 512]);
        gload16(bsrc1 + kb * 8192, &Bs[nb][(2 * w + 1) * 512]);
        // compute previous buffer
        bf16x8 af[4], bfr[4];
#pragma unroll
        for (int f = 0; f < 4; f++) af[f]  = *(const bf16x8*)&As[cb][aoff[f]];
#pragma unroll
        for (int f = 0; f < 4; f++) bfr[f] = *(const bf16x8*)&Bs[cb][boff[f]];
#pragma unroll
        for (int fm = 0; fm < 4; fm++)
#pragma unroll
            for (int fn = 0; fn < 4; fn++)
                acc[fm][fn] = __builtin_amdgcn_mfma_f32_16x16x32_bf16(af[fm], bfr[fn], acc[fm][fn], 0, 0, 0);
        // construct next A (loads hidden under compute)
        uint4 q;
        q.x = cvt_pk_bf16(fmaxf(u0.x + v0.x, 0.f), fmaxf(u0.y + v0.y, 0.f));
        q.y = cvt_pk_bf16(fmaxf(u0.z + v0.z, 0.f), fmaxf(u0.w + v0.w, 0.f));
        q.z = cvt_pk_bf16(fmaxf(u1.x + v1.x, 0.f), fmaxf(u1.y + v1.y, 0.f));
        q.w = cvt_pk_bf16(fmaxf(u1.z + v1.z, 0.f), fmaxf(u1.w + v1.w, 0.f));
        *(uint4*)&As[nb][awoff] = q;
    }
    __syncthreads();
    {
        bf16x8 af[4], bfr[4];
#pragma unroll
        for (int f = 0; f < 4; f++) af[f]  = *(const bf16x8*)&As[1][aoff[f]];
#pragma unroll
        for (int f = 0; f < 4; f++) bfr[f] = *(const bf16x8*)&Bs[1][boff[f]];
#pragma unroll
        for (int fm = 0; fm < 4; fm++)
#pragma unroll
            for (int fn = 0; fn < 4; fn++)
                acc[fm][fn] = __builtin_amdgcn_mfma_f32_16x16x32_bf16(af[fm], bfr[fn], acc[fm][fn], 0, 0, 0);
    }

    // Epilogue: bias+relu, row-sum over 31 real slots per receiver, /31.
#pragma unroll
    for (int fn = 0; fn < 4; fn++) {
        const int col = wn * 64 + fn * 16 + lr;
        const float bv = b2[col];
#pragma unroll
        for (int h = 0; h < 2; h++) {          // receiver within wave half
            float sum = 0.f;
#pragma unroll
            for (int q = 0; q < 2; q++) {
                const int fm = 2 * h + q;
#pragma unroll
                for (int r = 0; r < 4; r++) {
                    float v = acc[fm][fn][r] + bv;
                    v = fmaxf(v, 0.f);
                    if (!(q == 1 && lg == 3 && r == 3)) sum += v;  // skip slot 31
                }
            }
            sum += __shfl_xor(sum, 16);
            sum += __shfl_xor(sum, 32);
            if (lane < 16) {
                const int node = g0 + 2 * wm + h;
                agg[(size_t)node * 256 + col] = f2bf(sum * (1.0f / 31.0f));
            }
        }
    }
}

// ---------------------------------------------------------------------------
extern "C" void kernel_launch(void* const* d_in, const int* in_sizes, int n_in,
                              void* d_out, int out_size, void* d_ws, size_t ws_size,
                              hipStream_t stream)
{
    const float* x     = (const float*)d_in[0];
    const float* w_in1 = (const float*)d_in[3];
    const float* b_in1 = (const float*)d_in[4];
    const float* w_in2 = (const float*)d_in[5];
    const float* b_in2 = (const float*)d_in[6];
    const float* w_e1  = (const float*)d_in[7];
    const float* b_e1  = (const float*)d_in[8];
    const float* w_e2  = (const float*)d_in[9];
    const float* b_e2  = (const float*)d_in[10];
    const float* w_n1  = (const float*)d_in[11];
    const float* b_n1  = (const float*)d_in[12];
    const float* w_n2  = (const float*)d_in[13];
    const float* b_n2  = (const float*)d_in[14];

    char* ws = (char*)d_ws;
    size_t off = 0;
    auto alloc = [&](size_t n) { char* p = ws + off; off += (n + 255) & ~(size_t)255; return p; };

    ushort_t* wt  = (ushort_t*)alloc(7 * 65536 * sizeof(ushort_t));
    ushort_t* xb  = (ushort_t*)alloc(8192 * 256 * 2);
    ushort_t* h   = (ushort_t*)alloc(8192 * 256 * 2);
    ushort_t* t1  = (ushort_t*)alloc(8192 * 256 * 2);
    float*    UVf = (float*)   alloc(8192 * 512 * 4);
    ushort_t* ag  = (ushort_t*)alloc(8192 * 256 * 2);
    (void)ws_size; (void)in_sizes; (void)n_in; (void)out_size;

    prep_weights<<<56, 256, 0, stream>>>(w_in1, w_in2, w_e1, w_e2, w_n1, w_n2, wt);
    conv_x<<<1024, 256, 0, stream>>>(x, xb, 262144);

    dim3 gs(128, 4);
    gemm64<2><<<gs, 256, 0, stream>>>(xb, wt + 0 * 65536, b_in1, t1, 256);
    gemm64<2><<<gs, 256, 0, stream>>>(t1, wt + 1 * 65536, b_in2, h, 256);

    for (int p = 0; p < 2; p++) {
        // U' = h@We1_top + b_e1 (f32), V = h@We1_bot (f32), interleaved [node][512]
        gemm64<1><<<gs, 256, 0, stream>>>(h, wt + 2 * 65536, b_e1, UVf, 512);
        gemm64<0><<<gs, 256, 0, stream>>>(h, wt + 3 * 65536, nullptr, UVf + 256, 512);
        edge_fused<<<2048, 512, 0, stream>>>(UVf, wt + 4 * 65536, b_e2, ag);
        gemm64<2><<<gs, 256, 0, stream>>>(ag, wt + 5 * 65536, b_n1, t1, 256);
        if (p == 0)
            gemm64<2><<<gs, 256, 0, stream>>>(t1, wt + 6 * 65536, b_n2, h, 256);
        else
            gemm64<3><<<gs, 256, 0, stream>>>(t1, wt + 6 * 65536, b_n2, (float*)d_out, 256);
    }
}